// Round 5
// baseline (191.058 us; speedup 1.0000x reference)
//
#include <hip/hip_runtime.h>

#define B_DIM 4096
#define L_DIM 4096
#define SEGLEN 256
#define NSEG (L_DIM / SEGLEN)   // 16
#define WARM 512                // coupling window (proven exact)
#define CHUNK 64                // time steps per chunk
#define CF4 (CHUNK / 4)         // 16 float4 per row per chunk
#define LSTRIDE 68              // LDS floats per row: 64 + 4 pad

// ws layout: float C_acc[4096], float ts_acc[4096], int first_acc[4096]
__global__ __launch_bounds__(256) void init_kernel(float* wsf, int* wsi) {
    int i = blockIdx.x * 256 + threadIdx.x;
    if (i < 2 * B_DIM) wsf[i] = 0.f;
    if (i < B_DIM) wsi[i] = L_DIM;  // min-identity for first-spike
}

// Exact IEEE step (proven absmax 0): q = RN(u/20) via Markstein, compare off
// the dependent chain: u' = sp_prev ? I' : ((u - q) + I')
#define LIF_CORE(IIN)                         \
    float q0 = u * cdiv;                      \
    float rr = fmaf(-20.0f, q0, u);           \
    float q  = fmaf(rr, cdiv, q0);            \
    float a  = u - q;                         \
    float b  = a + (IIN);                     \
    u = sp ? (IIN) : b;                       \
    sp = (u >= 1.0f);

#define WARM_STEP(IIN) { LIF_CORE(IIN) }

#define FULL_STEP(IIN, SOUT)                  \
    {                                         \
        LIF_CORE(IIN)                         \
        float sf = sp ? 1.0f : 0.0f;          \
        cnt += sf;                            \
        seen = fmaxf(seen, sf);               \
        accS += cnt;                          \
        accF += seen;                         \
        (SOUT) = sf;                          \
    }

// Fully decoupled design: each wave owns 64 rows x one 256-step segment and
// is self-contained -- NO barriers, NO producer wave, NO cross-wave coupling.
// Wave-private LDS buffer (17 KB) is used as a transpose stage both ways:
//   input : coalesced global load (lane=(srow,scol): 4 x 256B segments/instr)
//           -> ds_write -> transposed ds_read (row-per-lane) -> R regs
//   spikes: ds_write row-major during compute -> coalesced ds_read into 16
//           DISTINCT S regs (no store-source reuse -> no store-wait stalls)
//           -> full-line coalesced global stores (never waited on in-loop)
// Same-wave LDS ops execute in order (in-order LDS pipe; the read-then-
// overwrite aliasing in rounds 2-4 relied on this and verified absmax 0),
// so every handoff is just a counted lgkmcnt the compiler inserts.
// Prefetch depth 1: chunk c+1 global loads issue before computing chunk c
// (~1.6k cycles of slack vs ~900-cycle HBM latency).
// Grid: 1024 waves = 512 blocks x 2 waves; LDS 34816/block -> 2 blocks/CU,
// 4 waves/CU = 1/SIMD. The LIF chain is issue-dense (~22 issue vs 24 chain
// cycles per step), so one wave/SIMD nearly saturates it during compute.
__global__ __launch_bounds__(128, 1) void lif_kernel(const float* __restrict__ I,
                                                     float* __restrict__ out,
                                                     float* __restrict__ Cacc,
                                                     float* __restrict__ tsAcc,
                                                     int* __restrict__ firstAcc) {
    __shared__ __align__(16) float lds[2][64 * LSTRIDE];
    const int wid = threadIdx.x >> 6;
    const int lane = threadIdx.x & 63;
    float* buf = &lds[wid][0];

    // 512 blocks: rowgroup = b>>3 (64), segpair = b&7; wave seg = 2*sp + wid
    const int rowBase = (blockIdx.x >> 3) * 64;
    const int seg = ((blockIdx.x & 7) << 1) + wid;
    const int t0 = seg * SEGLEN;
    const int start = (t0 > WARM) ? (t0 - WARM) : 0;
    const int nwarmCh = (t0 - start) / CHUNK;     // 0, 4, or 8
    const int nch = nwarmCh + SEGLEN / CHUNK;     // 4, 8, or 12

    const int srow = lane >> 4, scol = lane & 15;  // coalesced lane mapping
    const float* gb = I + (size_t)rowBase * L_DIM + start + scol * 4;
    float* ob = out + (size_t)rowBase * L_DIM + t0 + scol * 4;

    const int row = rowBase + lane;
    float u = 0.f, cnt = 0.f, seen = 0.f, accS = 0.f, accF = 0.f;
    bool sp = false;
    const float cdiv = 0.05f;  // RN(1/20)

    float4 G[16], R[16];

    // prologue: chunk 0 -> LDS -> R (one exposed load latency, once)
#pragma unroll
    for (int p = 0; p < 16; ++p)
        G[p] = *(const float4*)(gb + (size_t)(4 * p + srow) * L_DIM);
#pragma unroll
    for (int p = 0; p < 16; ++p)
        *(float4*)&buf[(4 * p + srow) * LSTRIDE + scol * 4] = G[p];
#pragma unroll
    for (int j = 0; j < 16; ++j)
        R[j] = *(const float4*)&buf[lane * LSTRIDE + 4 * j];

    for (int c = 0; c < nch; ++c) {
        // 1. issue coalesced prefetch of chunk c+1 (hides under compute)
        if (c + 1 < nch) {
            const float* g = gb + (c + 1) * CHUNK;
#pragma unroll
            for (int p = 0; p < 16; ++p)
                G[p] = *(const float4*)(g + (size_t)(4 * p + srow) * L_DIM);
        }
        __builtin_amdgcn_sched_barrier(0);  // keep prefetch ahead of compute

        // 2. compute chunk c from R (row-per-lane)
        if (c < nwarmCh) {
#pragma unroll
            for (int j = 0; j < 16; ++j) {
                float4 iv = R[j];
                WARM_STEP(iv.x) WARM_STEP(iv.y) WARM_STEP(iv.z) WARM_STEP(iv.w)
            }
        } else {
#pragma unroll
            for (int j = 0; j < 16; ++j) {
                float4 iv = R[j];
                float4 sv;
                FULL_STEP(iv.x, sv.x) FULL_STEP(iv.y, sv.y)
                FULL_STEP(iv.z, sv.z) FULL_STEP(iv.w, sv.w)
                *(float4*)&buf[lane * LSTRIDE + 4 * j] = sv;  // spikes row-major
            }
            // 3. transpose spikes via LDS, coalesced full-line stores.
            //    16 distinct S regs: stores never block an S reload.
            float4 S[16];
            float* og = ob + (size_t)(c - nwarmCh) * CHUNK;
#pragma unroll
            for (int p = 0; p < 16; ++p)
                S[p] = *(const float4*)&buf[(4 * p + srow) * LSTRIDE + scol * 4];
#pragma unroll
            for (int p = 0; p < 16; ++p)
                *(float4*)(og + (size_t)(4 * p + srow) * L_DIM) = S[p];
        }

        // 4. stage chunk c+1 into LDS (counted vmcnt for G; spike stores are
        //    younger and stay in flight), then transposed read into R
        if (c + 1 < nch) {
#pragma unroll
            for (int p = 0; p < 16; ++p)
                *(float4*)&buf[(4 * p + srow) * LSTRIDE + scol * 4] = G[p];
#pragma unroll
            for (int j = 0; j < 16; ++j)
                R[j] = *(const float4*)&buf[lane * LSTRIDE + 4 * j];
        }
    }

    // per-segment partials (exact integers < 2^24 -> float atomics exact)
    if (cnt > 0.f) {
        const int firstLocal = (int)((float)SEGLEN - accF);
        atomicMin(&firstAcc[row], t0 + firstLocal);
    }
    atomicAdd(&Cacc[row], cnt);
    atomicAdd(&tsAcc[row], fmaf((float)(t0 + SEGLEN), cnt, -accS));
}

__global__ __launch_bounds__(256) void fin_kernel(const float* __restrict__ Cacc,
                                                  const float* __restrict__ tsAcc,
                                                  const int* __restrict__ firstAcc,
                                                  float* __restrict__ out) {
    int r = blockIdx.x * 256 + threadIdx.x;
    if (r < B_DIM) {
        out[(size_t)B_DIM * L_DIM + r] = (float)firstAcc[r];
        out[(size_t)B_DIM * L_DIM + B_DIM + r] = tsAcc[r] / (Cacc[r] + 1e-6f);
    }
}

extern "C" void kernel_launch(void* const* d_in, const int* in_sizes, int n_in,
                              void* d_out, int out_size, void* d_ws, size_t ws_size,
                              hipStream_t stream) {
    const float* I = (const float*)d_in[0];
    float* out = (float*)d_out;
    float* wsf = (float*)d_ws;
    int* wsi = (int*)((float*)d_ws + 2 * B_DIM);
    (void)in_sizes; (void)n_in; (void)out_size; (void)ws_size;

    init_kernel<<<(2 * B_DIM + 255) / 256, 256, 0, stream>>>(wsf, wsi);
    lif_kernel<<<(NSEG / 2) * 64, 128, 0, stream>>>(I, out, wsf, wsf + B_DIM, wsi);
    fin_kernel<<<(B_DIM + 255) / 256, 256, 0, stream>>>(wsf, wsf + B_DIM, wsi, out);
}

// Round 6
// 137.940 us; speedup vs baseline: 1.3851x; 1.3851x over previous
//
#include <hip/hip_runtime.h>

#define B_DIM 4096
#define L_DIM 4096
#define SEGLEN 256
#define NSEG (L_DIM / SEGLEN)   // 16
#define WARM 512                // coupling window (proven exact)
#define CHUNK 64                // time steps per chunk
#define LROW 64                 // LDS floats per row: LINEAR (global_load_lds dest)

// ws layout: float C_acc[4096], float ts_acc[4096], int first_acc[4096]
__global__ __launch_bounds__(256) void init_kernel(float* wsf, int* wsi) {
    int i = blockIdx.x * 256 + threadIdx.x;
    if (i < 2 * B_DIM) wsf[i] = 0.f;
    if (i < B_DIM) wsi[i] = L_DIM;  // min-identity for first-spike
}

// Exact IEEE step (proven absmax 0): q = RN(u/20) via Markstein, compare off
// the dependent chain: u' = sp_prev ? I' : ((u - q) + I')
#define LIF_CORE(IIN)                         \
    float q0 = u * cdiv;                      \
    float rr = fmaf(-20.0f, q0, u);           \
    float q  = fmaf(rr, cdiv, q0);            \
    float a  = u - q;                         \
    float b  = a + (IIN);                     \
    u = sp ? (IIN) : b;                       \
    sp = (u >= 1.0f);

#define WARM_STEP(IIN) { LIF_CORE(IIN) }

#define FULL_STEP(IIN, SOUT)                  \
    {                                         \
        LIF_CORE(IIN)                         \
        float sf = sp ? 1.0f : 0.0f;          \
        cnt += sf;                            \
        seen = fmaxf(seen, sf);               \
        accS += cnt;                          \
        accF += seen;                         \
        (SOUT) = sf;                          \
    }

typedef const __attribute__((address_space(1))) void g_void;
typedef __attribute__((address_space(3))) void l_void;
__device__ __forceinline__ void gll16(const float* src, float* ldsbase) {
    // async global->LDS, 16B/lane; LDS dest = wave-uniform base + lane*16B
    __builtin_amdgcn_global_load_lds((g_void*)src, (l_void*)ldsbase, 16, 0, 0);
}

// Fully decoupled: each wave owns 64 rows x one 256-step segment; zero
// barriers, zero cross-wave coupling. Round-5 disease was REGISTER SPILL
// (G[16]+R[16]+S[16] live > VGPR budget -> scratch = hidden global traffic,
// the real source of rounds 3-5 "write amplification"). Fix: stage input
// via global_load_lds (no staging registers at all; peak live ~90 VGPR).
//
// gll needs a LINEAR LDS dest (LROW=64, no pad). Bank fix per rule #21
// (both-sides-or-neither): inverse-swizzle the PER-LANE GLOBAL source
// (colblock (scol-row)&15) + same swizzle on transposed reads/writes
// (slot k=(j+row)&15). LDS slot (row,k) holds global block (k-row)&15.
// All three wave patterns -> 8 dwords/bank = ds_*_b128 optimum.
//
// Per-iter vmcnt discipline (clean writes, hidden latency):
//   [issue 16x gll(c+1)] [compute c from R; spikes -> bufc swizzled]
//   [S <- bufc linear; 16 coalesced stores (col-permuted)]
//   [vmcnt(16): retains this iter's stores; drains gll(c+1) + prior stores]
//   [R <- bufn transposed-swizzled]
// Stores live <=1 iter (write-back clean); gll waited only after a full
// compute phase of slack. Warm iters: vmcnt(0) (no stores outstanding).
__global__ __launch_bounds__(128, 1) void lif_kernel(const float* __restrict__ I,
                                                     float* __restrict__ out,
                                                     float* __restrict__ Cacc,
                                                     float* __restrict__ tsAcc,
                                                     int* __restrict__ firstAcc) {
    __shared__ __align__(16) float lds[2][2][64 * LROW];  // [wave][dbuf] 64KB
    const int wid = threadIdx.x >> 6;
    const int lane = threadIdx.x & 63;
    float* buf0 = &lds[wid][0][0];
    float* buf1 = &lds[wid][1][0];

    // 512 blocks: rowgroup = b>>3; segpair = b&7; wave seg = 2*pair + wid
    // (adjacent segs share a block -> their warm windows overlap in L2)
    const int rowBase = (blockIdx.x >> 3) * 64;
    const int seg = ((blockIdx.x & 7) << 1) + wid;
    const int t0 = seg * SEGLEN;
    const int start = (t0 > WARM) ? (t0 - WARM) : 0;
    const int nwarmCh = (t0 - start) / CHUNK;     // 0, 4, or 8
    const int nch = nwarmCh + SEGLEN / CHUNK;     // 4, 8, or 12

    const int srow = lane >> 4, scol = lane & 15;
    const float* gbase = I + (size_t)rowBase * L_DIM + start;

    const int row = rowBase + lane;
    float u = 0.f, cnt = 0.f, seen = 0.f, accS = 0.f, accF = 0.f;
    bool sp = false;
    const float cdiv = 0.05f;  // RN(1/20)
    float4 R[16];

#define GLL_CHUNK(CC, DST)                                                  \
    {                                                                       \
        const float* gsrc = gbase + (size_t)(CC) * CHUNK;                   \
        _Pragma("unroll")                                                   \
        for (int p = 0; p < 16; ++p) {                                      \
            const int r = 4 * p + srow;                                     \
            gll16(gsrc + (size_t)r * L_DIM + (((scol - r) & 15) << 2),      \
                  (DST) + p * 256);                                         \
        }                                                                   \
    }

#define READ_R(SRC)                                                         \
    {                                                                       \
        _Pragma("unroll")                                                   \
        for (int j = 0; j < 16; ++j)                                        \
            R[j] = *(const float4*)&(SRC)[lane * LROW + (((j + lane) & 15) << 2)]; \
    }

    // prologue: chunk 0 -> LDS -> R (one exposed latency, once)
    GLL_CHUNK(0, buf0)
    asm volatile("s_waitcnt vmcnt(0)" ::: "memory");
    __builtin_amdgcn_sched_barrier(0);
    READ_R(buf0)

    for (int c = 0; c < nch; ++c) {
        float* bufc = (c & 1) ? buf1 : buf0;
        float* bufn = (c & 1) ? buf0 : buf1;

        // 1. async-stage chunk c+1 (no registers consumed)
        if (c + 1 < nch) GLL_CHUNK(c + 1, bufn)
        __builtin_amdgcn_sched_barrier(0);

        // 2. compute chunk c from R
        if (c < nwarmCh) {
#pragma unroll
            for (int j = 0; j < 16; ++j) {
                float4 iv = R[j];
                WARM_STEP(iv.x) WARM_STEP(iv.y) WARM_STEP(iv.z) WARM_STEP(iv.w)
            }
        } else {
            // spikes overwrite bufc (input c fully consumed into R; same-wave
            // in-order LDS). Swizzled slots k=(j+lane)&15.
#pragma unroll
            for (int j = 0; j < 16; ++j) {
                float4 iv = R[j];
                float4 sv;
                FULL_STEP(iv.x, sv.x) FULL_STEP(iv.y, sv.y)
                FULL_STEP(iv.z, sv.z) FULL_STEP(iv.w, sv.w)
                *(float4*)&bufc[lane * LROW + (((j + lane) & 15) << 2)] = sv;
            }
            // 3. coalesced spike store: linear LDS read (srow,scol) holds
            //    out-block (scol-r)&15 -> store to that global block.
            float4 S[16];
#pragma unroll
            for (int p = 0; p < 16; ++p)
                S[p] = *(const float4*)&bufc[p * 256 + lane * 4];
            float* og = out + (size_t)rowBase * L_DIM + t0 +
                        (size_t)(c - nwarmCh) * CHUNK;
#pragma unroll
            for (int p = 0; p < 16; ++p) {
                const int r = 4 * p + srow;
                *(float4*)(og + (size_t)r * L_DIM + (((scol - r) & 15) << 2)) = S[p];
            }
        }

        // 4. counted drain + next-chunk register load
        if (c + 1 < nch) {
            if (c >= nwarmCh) {
                // retain this iter's 16 stores; drain gll(c+1) + older stores
                asm volatile("s_waitcnt vmcnt(16)" ::: "memory");
            } else {
                asm volatile("s_waitcnt vmcnt(0)" ::: "memory");
            }
            __builtin_amdgcn_sched_barrier(0);
            READ_R(bufn)
        }
    }

    // per-segment partials (exact integers < 2^24 -> float atomics exact)
    if (cnt > 0.f) {
        const int firstLocal = (int)((float)SEGLEN - accF);
        atomicMin(&firstAcc[row], t0 + firstLocal);
    }
    atomicAdd(&Cacc[row], cnt);
    atomicAdd(&tsAcc[row], fmaf((float)(t0 + SEGLEN), cnt, -accS));
#undef GLL_CHUNK
#undef READ_R
}

__global__ __launch_bounds__(256) void fin_kernel(const float* __restrict__ Cacc,
                                                  const float* __restrict__ tsAcc,
                                                  const int* __restrict__ firstAcc,
                                                  float* __restrict__ out) {
    int r = blockIdx.x * 256 + threadIdx.x;
    if (r < B_DIM) {
        out[(size_t)B_DIM * L_DIM + r] = (float)firstAcc[r];
        out[(size_t)B_DIM * L_DIM + B_DIM + r] = tsAcc[r] / (Cacc[r] + 1e-6f);
    }
}

extern "C" void kernel_launch(void* const* d_in, const int* in_sizes, int n_in,
                              void* d_out, int out_size, void* d_ws, size_t ws_size,
                              hipStream_t stream) {
    const float* I = (const float*)d_in[0];
    float* out = (float*)d_out;
    float* wsf = (float*)d_ws;
    int* wsi = (int*)((float*)d_ws + 2 * B_DIM);
    (void)in_sizes; (void)n_in; (void)out_size; (void)ws_size;

    init_kernel<<<(2 * B_DIM + 255) / 256, 256, 0, stream>>>(wsf, wsi);
    lif_kernel<<<(B_DIM / 64) * (NSEG / 2), 128, 0, stream>>>(I, out, wsf, wsf + B_DIM, wsi);
    fin_kernel<<<(B_DIM + 255) / 256, 256, 0, stream>>>(wsf, wsf + B_DIM, wsi, out);
}